// Round 11
// baseline (166.751 us; speedup 1.0000x reference)
//
#include <hip/hip_runtime.h>

#define BATCH 65536
#define MT 64                 // rows per block
#define NBLK (BATCH / MT)     // 1024

typedef unsigned short u16;
typedef __bf16 bf16x8 __attribute__((ext_vector_type(8)));
typedef float f32x4 __attribute__((ext_vector_type(4)));

// d_ws u16 region: fragment-native weights (R6 layout)
//   W'[K32][col][g][e]: element (col,k) at K32*16384 + col*32 + (k>>3&3)*8 + (k&7)
#define WI_OFF 0              // [512][4][8] (k>=16 zero)
#define WH_OFF 16384          // 2 layers x 16 tiles
#define WO_OFF 540672         // [16][32][4][8] (o padded 17->32)
#define WS_USH 557056
// float region at byte 1,114,112
#define BI_F 0
#define BH_F 512
#define BO_F 1536
#define PART_F 4096           // [1024][2]
#define SCALE_F 8192          // [65536]
// X activation buffers (bf16 [65536][512], swizzled rows), byte offsets in d_ws
#define X1_OFF (2u * 1024u * 1024u)
#define X2_OFF (X1_OFF + 67108864u)
#define X3_OFF (X2_OFF + 67108864u)

#define PREP_WH 65536
#define PREP_WI 2048
#define PREP_WO 2048
#define PREP_SC 1568
#define PREP_TOTAL (PREP_WH + PREP_WI + PREP_WO + PREP_SC)

__device__ inline u16 f2bf(float f) {
  union { float f; unsigned u; } v; v.f = f;
  unsigned u = v.u + 0x7fffu + ((v.u >> 16) & 1u);   // RNE
  return (u16)(u >> 16);
}

__global__ void prep_kernel(const float* __restrict__ w_in, const float* __restrict__ b_in,
                            const float* __restrict__ w_hid, const float* __restrict__ b_hid,
                            const float* __restrict__ w_out, const float* __restrict__ b_out,
                            const int* __restrict__ variant, int n,
                            u16* __restrict__ wsu, float* __restrict__ wsf)
{
  const int model = (n - 5) * 16 + variant[0];
  const int i = blockIdx.x * 256 + threadIdx.x;
  if (i < PREP_WH) {
    int g = i & 3, col = (i >> 2) & 511, K32 = (i >> 11) & 15, l = i >> 15;
    const float* src = w_hid + (size_t)model * 524288 + (size_t)l * 262144 + col * 512 + K32 * 32 + g * 8;
    u16* dst = wsu + WH_OFF + (size_t)i * 8;
    #pragma unroll
    for (int e = 0; e < 8; ++e) dst[e] = f2bf(src[e]);
  } else if (i < PREP_WH + PREP_WI) {
    int j = i - PREP_WH;
    int g = j & 3, col = j >> 2;
    u16* dst = wsu + WI_OFF + (size_t)j * 8;
    #pragma unroll
    for (int e = 0; e < 8; ++e) {
      int k = g * 8 + e;
      dst[e] = (k < 16) ? f2bf(w_in[(size_t)model * 8192 + col * 16 + k]) : (u16)0;
    }
  } else if (i < PREP_WH + PREP_WI + PREP_WO) {
    int j = i - PREP_WH - PREP_WI;
    int g = j & 3, col = (j >> 2) & 31, K32 = j >> 7;
    u16* dst = wsu + WO_OFF + (size_t)j * 8;
    #pragma unroll
    for (int e = 0; e < 8; ++e) {
      int k = K32 * 32 + g * 8 + e;
      dst[e] = (col < 17) ? f2bf(w_out[(size_t)model * 8704 + col * 512 + k]) : (u16)0;
    }
  } else if (i < PREP_TOTAL) {
    int j = i - PREP_WH - PREP_WI - PREP_WO;
    if (j < 512)       wsf[BI_F + j] = b_in[(size_t)model * 512 + j];
    else if (j < 1536) wsf[BH_F + (j - 512)] = b_hid[(size_t)model * 1024 + (j - 512)];
    else               { int o = j - 1536; wsf[BO_F + o] = (o < 17) ? b_out[(size_t)model * 17 + o] : 0.f; }
  }
}

// swizzled activation addressing: byte = row*1024 + ((col*2) ^ ((row&15)<<4))
__device__ __forceinline__ bf16x8 rdA(const char* xb, int row, int kbyte) {
  return *reinterpret_cast<const bf16x8*>(xb + row * 1024 + (kbyte ^ ((row & 15) << 4)));
}
__device__ __forceinline__ void stG(char* X, size_t grow, int col, u16 v) {
  *(u16*)(X + grow * 1024 + ((col * 2) ^ (((int)(grow & 15)) << 4))) = v;
}

__device__ __forceinline__ void stage16(const char* g, const char* l) {
  __builtin_amdgcn_global_load_lds(
      (const __attribute__((address_space(1))) unsigned int*)(uintptr_t)g,
      (__attribute__((address_space(3))) unsigned int*)(unsigned)(uintptr_t)l,
      16, 0, 0);
}

// ---------------- K0: normalize + input layer (K=32), write X1 swizzled ----------------
template<int CN>
__global__ __launch_bounds__(256, 2) void layer0_kernel(
    const float* __restrict__ T, const u16* __restrict__ wsu, const float* __restrict__ wsf,
    char* __restrict__ X1, float* __restrict__ scaleArr, int n_arg)
{
  const int n = CN ? CN : n_arg;
  __shared__ u16 xs0[64 * 40];          // row stride 80B (16B-aligned, 2-way max)
  const int tid = threadIdx.x, blk = blockIdx.x;
  const int lane = tid & 63, wid = tid >> 6;
  const int l15 = lane & 15, q = lane >> 4;
  const int c0 = wid * 128;

  {
    const int r = tid >> 2, j = tid & 3;
    const size_t gr = (size_t)blk * MT + r;
    float v[4];
    if (CN == 16) {
      float4 t4 = reinterpret_cast<const float4*>(T + gr * 16)[j];
      v[0] = t4.x; v[1] = t4.y; v[2] = t4.z; v[3] = t4.w;
    } else {
      #pragma unroll
      for (int c = 0; c < 4; ++c) { int k = j * 4 + c; v[c] = (k < n) ? T[gr * n + k] : 0.f; }
    }
    float ss = v[0]*v[0] + v[1]*v[1] + v[2]*v[2] + v[3]*v[3];
    ss += __shfl_xor(ss, 1); ss += __shfl_xor(ss, 2);
    float norm = sqrtf(ss < 1e-12f ? 1e-12f : ss);
    float rn = 1.f / norm;
    if (j == 0) scaleArr[gr] = sqrtf(norm);
    #pragma unroll
    for (int c = 0; c < 4; ++c) {
      xs0[r * 40 + j * 4 + c] = f2bf(v[c] * rn);
      xs0[r * 40 + 16 + j * 4 + c] = 0;
    }
  }
  __syncthreads();

  f32x4 acc[4][8];
  #pragma unroll
  for (int a = 0; a < 4; ++a)
    #pragma unroll
    for (int b = 0; b < 8; ++b) { f32x4 z = {0.f,0.f,0.f,0.f}; acc[a][b] = z; }

  const u16* Wl = wsu + WI_OFF + (c0 + l15) * 32 + q * 8;
  uint4 b0[8];
  #pragma unroll
  for (int ct = 0; ct < 8; ++ct)
    b0[ct] = *reinterpret_cast<const uint4*>(Wl + ct * 512);
  #pragma unroll
  for (int mt = 0; mt < 4; ++mt) {
    bf16x8 a = *reinterpret_cast<const bf16x8*>(&xs0[(mt * 16 + l15) * 40 + q * 8]);
    #pragma unroll
    for (int ct = 0; ct < 8; ++ct)
      acc[mt][ct] = __builtin_amdgcn_mfma_f32_16x16x32_bf16(
          a, __builtin_bit_cast(bf16x8, b0[ct]), acc[mt][ct], 0, 0, 0);
  }

  float bv[8];
  #pragma unroll
  for (int ct = 0; ct < 8; ++ct) bv[ct] = wsf[BI_F + c0 + ct * 16 + l15];
  #pragma unroll
  for (int mt = 0; mt < 4; ++mt)
    #pragma unroll
    for (int ct = 0; ct < 8; ++ct)
      #pragma unroll
      for (int j = 0; j < 4; ++j) {
        int rl = mt * 16 + q * 4 + j;
        size_t gr = (size_t)blk * MT + rl;
        float z = acc[mt][ct][j] + bv[ct];
        float h = z / (1.f + __expf(-z));
        stG(X1, gr, c0 + ct * 16 + l15, f2bf(h));
      }
}

// ---------------- hidden layer: X_in(64MB, swizzled) -> relu -> X_out ----------------
__global__ __launch_bounds__(256, 2) void hidden_kernel(
    const char* __restrict__ Xin, const u16* __restrict__ Wbase,
    const float* __restrict__ bias, char* __restrict__ Xout)
{
  __shared__ u16 xs[MT * 512];          // 64 KiB A-tile (swizzle pre-applied in global)
  const int tid = threadIdx.x, blk = blockIdx.x;
  const int lane = tid & 63, wid = tid >> 6;
  const int l15 = lane & 15, q = lane >> 4;
  const int c0 = wid * 128;
  char* xb = (char*)xs;

  // stage whole A-tile linearly (swizzle already in memory)
  {
    const char* src = Xin + (size_t)blk * 65536;
    #pragma unroll
    for (int r2 = 0; r2 < 16; ++r2)
      stage16(src + tid * 16 + r2 * 4096, xb + tid * 16 + r2 * 4096);
  }
  asm volatile("s_waitcnt vmcnt(0)" ::: "memory");
  __syncthreads();

  f32x4 acc[4][8];
  #pragma unroll
  for (int a = 0; a < 4; ++a)
    #pragma unroll
    for (int b = 0; b < 8; ++b) { f32x4 z = {0.f,0.f,0.f,0.f}; acc[a][b] = z; }

  const u16* Wl = Wbase + (c0 + l15) * 32 + q * 8;
  uint4 bc[8], bn[8];
  #pragma unroll
  for (int ct = 0; ct < 8; ++ct)
    bc[ct] = *reinterpret_cast<const uint4*>(Wl + ct * 512);

  #pragma unroll 1
  for (int i = 0; i < 16; i += 2) {
    {
      const u16* p = Wl + (size_t)(i + 1) * 16384;
      #pragma unroll
      for (int ct = 0; ct < 8; ++ct)
        bn[ct] = *reinterpret_cast<const uint4*>(p + ct * 512);
    }
    {
      const int kb = i * 64 + q * 16;
      #pragma unroll
      for (int mt = 0; mt < 4; ++mt) {
        bf16x8 a = rdA(xb, mt * 16 + l15, kb);
        #pragma unroll
        for (int ct = 0; ct < 8; ++ct)
          acc[mt][ct] = __builtin_amdgcn_mfma_f32_16x16x32_bf16(
              a, __builtin_bit_cast(bf16x8, bc[ct]), acc[mt][ct], 0, 0, 0);
      }
    }
    {
      const u16* p = Wl + (size_t)((i + 2) & 15) * 16384;
      #pragma unroll
      for (int ct = 0; ct < 8; ++ct)
        bc[ct] = *reinterpret_cast<const uint4*>(p + ct * 512);
    }
    {
      const int kb = (i + 1) * 64 + q * 16;
      #pragma unroll
      for (int mt = 0; mt < 4; ++mt) {
        bf16x8 a = rdA(xb, mt * 16 + l15, kb);
        #pragma unroll
        for (int ct = 0; ct < 8; ++ct)
          acc[mt][ct] = __builtin_amdgcn_mfma_f32_16x16x32_bf16(
              a, __builtin_bit_cast(bf16x8, bn[ct]), acc[mt][ct], 0, 0, 0);
      }
    }
  }

  float bv[8];
  #pragma unroll
  for (int ct = 0; ct < 8; ++ct) bv[ct] = bias[c0 + ct * 16 + l15];
  #pragma unroll
  for (int mt = 0; mt < 4; ++mt)
    #pragma unroll
    for (int ct = 0; ct < 8; ++ct)
      #pragma unroll
      for (int j = 0; j < 4; ++j) {
        int rl = mt * 16 + q * 4 + j;
        size_t gr = (size_t)blk * MT + rl;
        float z = acc[mt][ct][j] + bv[ct];
        stG(Xout, gr, c0 + ct * 16 + l15, f2bf(fmaxf(z, 0.f)));
      }
}

// ---------------- K3: output layer + distortion ----------------
template<int CN>
__global__ __launch_bounds__(256, 2) void out_kernel(
    const float* __restrict__ T, const char* __restrict__ X3,
    const u16* __restrict__ wsu, const float* __restrict__ wsf,
    const float* __restrict__ scaleArr, float* __restrict__ Xout, float* __restrict__ Xcout,
    float* __restrict__ errPart, int n_arg)
{
  const int n = CN ? CN : n_arg;
  __shared__ u16 xs[MT * 512];
  __shared__ float xo[MT * 20];
  __shared__ float ered[4][2];
  const int tid = threadIdx.x, blk = blockIdx.x;
  const int lane = tid & 63, wid = tid >> 6;
  const int l15 = lane & 15, q = lane >> 4;
  char* xb = (char*)xs;

  {
    const char* src = X3 + (size_t)blk * 65536;
    #pragma unroll
    for (int r2 = 0; r2 < 16; ++r2)
      stage16(src + tid * 16 + r2 * 4096, xb + tid * 16 + r2 * 4096);
  }
  asm volatile("s_waitcnt vmcnt(0)" ::: "memory");
  __syncthreads();

  {
    f32x4 oacc[2];
    { f32x4 z = {0.f,0.f,0.f,0.f}; oacc[0] = z; oacc[1] = z; }
    const int bofs2 = l15 * 32 + q * 8;
    uint4 ob[2], on[2];
    #pragma unroll
    for (int ct = 0; ct < 2; ++ct)
      ob[ct] = *reinterpret_cast<const uint4*>(wsu + WO_OFF + bofs2 + ct * 512);
    #pragma unroll 1
    for (int K = 0; K < 16; K += 2) {
      #pragma unroll
      for (int ct = 0; ct < 2; ++ct)
        on[ct] = *reinterpret_cast<const uint4*>(wsu + WO_OFF + (size_t)(K + 1) * 1024 + bofs2 + ct * 512);
      {
        bf16x8 a = rdA(xb, wid * 16 + l15, K * 64 + q * 16);
        #pragma unroll
        for (int ct = 0; ct < 2; ++ct)
          oacc[ct] = __builtin_amdgcn_mfma_f32_16x16x32_bf16(
              a, __builtin_bit_cast(bf16x8, ob[ct]), oacc[ct], 0, 0, 0);
      }
      #pragma unroll
      for (int ct = 0; ct < 2; ++ct)
        ob[ct] = *reinterpret_cast<const uint4*>(wsu + WO_OFF + (size_t)((K + 2) & 15) * 1024 + bofs2 + ct * 512);
      {
        bf16x8 a = rdA(xb, wid * 16 + l15, (K + 1) * 64 + q * 16);
        #pragma unroll
        for (int ct = 0; ct < 2; ++ct)
          oacc[ct] = __builtin_amdgcn_mfma_f32_16x16x32_bf16(
              a, __builtin_bit_cast(bf16x8, on[ct]), oacc[ct], 0, 0, 0);
      }
    }
    #pragma unroll
    for (int ct = 0; ct < 2; ++ct)
      #pragma unroll
      for (int j = 0; j < 4; ++j) {
        int o = ct * 16 + l15;
        int rl = wid * 16 + q * 4 + j;
        size_t gr = (size_t)blk * MT + rl;
        if (o <= n) {
          float val = (oacc[ct][j] + wsf[BO_F + o]) * scaleArr[gr];
          float cv = fminf(fmaxf(val, -2.f), 2.f);
          Xout[gr * (n + 1) + o] = val;
          Xcout[gr * (n + 1) + o] = cv;
          xo[rl * 20 + o] = val;
        }
      }
  }
  __syncthreads();

  {
    const int r = tid >> 2, j = tid & 3;
    const size_t gr = (size_t)blk * MT + r;
    float x[17], cx[17];
    #pragma unroll
    for (int i = 0; i < 17; ++i) {
      float v = (i <= n) ? xo[r * 20 + i] : 0.f;
      x[i] = v; cx[i] = fminf(fmaxf(v, -2.f), 2.f);
    }
    float e = 0.f, ec = 0.f;
    #pragma unroll
    for (int kk = 0; kk < 4; ++kk) {
      int k = j + 1 + kk * 4;
      if (k <= n) {
        float d = 0.f, dc = 0.f;
        #pragma unroll
        for (int i = 0; i < 16; ++i) {
          if (i + k <= 16) {
            if (i + k <= n) { d += x[i] * x[i + k]; dc += cx[i] * cx[i + k]; }
          }
        }
        float tvv = T[gr * n + (n - k)];
        float r1 = d - tvv, r2 = dc - tvv;
        e += r1 * r1; ec += r2 * r2;
      }
    }
    e += __shfl_xor(e, 1);  ec += __shfl_xor(ec, 1);
    e += __shfl_xor(e, 2);  ec += __shfl_xor(ec, 2);
    e += __shfl_xor(e, 4);  ec += __shfl_xor(ec, 4);
    e += __shfl_xor(e, 8);  ec += __shfl_xor(ec, 8);
    e += __shfl_xor(e, 16); ec += __shfl_xor(ec, 16);
    e += __shfl_xor(e, 32); ec += __shfl_xor(ec, 32);
    if (lane == 0) { ered[wid][0] = e; ered[wid][1] = ec; }
  }
  __syncthreads();
  if (tid == 0) {
    float e = 0.f, ec = 0.f;
    #pragma unroll
    for (int w = 0; w < 4; ++w) { e += ered[w][0]; ec += ered[w][1]; }
    errPart[blk * 2]     = e;
    errPart[blk * 2 + 1] = ec;
  }
}

__global__ void finalize_kernel(const float* __restrict__ part, float* __restrict__ e0,
                                float* __restrict__ e1, float inv)
{
  __shared__ float se[4][2];
  const int t = threadIdx.x;           // 256 threads
  float e = 0.f, ec = 0.f;
  for (int b = t; b < NBLK; b += 256) { e += part[2 * b]; ec += part[2 * b + 1]; }
  e += __shfl_xor(e, 1);  ec += __shfl_xor(ec, 1);
  e += __shfl_xor(e, 2);  ec += __shfl_xor(ec, 2);
  e += __shfl_xor(e, 4);  ec += __shfl_xor(ec, 4);
  e += __shfl_xor(e, 8);  ec += __shfl_xor(ec, 8);
  e += __shfl_xor(e, 16); ec += __shfl_xor(ec, 16);
  e += __shfl_xor(e, 32); ec += __shfl_xor(ec, 32);
  if ((t & 63) == 0) { se[t >> 6][0] = e; se[t >> 6][1] = ec; }
  __syncthreads();
  if (t == 0) {
    float te = 0.f, tec = 0.f;
    #pragma unroll
    for (int w = 0; w < 4; ++w) { te += se[w][0]; tec += se[w][1]; }
    e0[0] = te * inv;
    e1[0] = tec * inv;
  }
}

extern "C" void kernel_launch(void* const* d_in, const int* in_sizes, int n_in,
                              void* d_out, int out_size, void* d_ws, size_t ws_size,
                              hipStream_t stream)
{
  const float* T       = (const float*)d_in[0];
  const int*   variant = (const int*)d_in[2];
  const float* w_in    = (const float*)d_in[3];
  const float* b_in    = (const float*)d_in[4];
  const float* w_hid   = (const float*)d_in[5];
  const float* b_hid   = (const float*)d_in[6];
  const float* w_out   = (const float*)d_in[7];
  const float* b_out   = (const float*)d_in[8];
  const int n = in_sizes[0] / BATCH;

  u16* wsu  = (u16*)d_ws;
  float* wsf = (float*)((char*)d_ws + (size_t)WS_USH * 2);
  char* X1 = (char*)d_ws + X1_OFF;
  char* X2 = (char*)d_ws + X2_OFF;
  char* X3 = (char*)d_ws + X3_OFF;
  float* scaleArr = wsf + SCALE_F;

  float* out = (float*)d_out;
  const size_t xe = (size_t)BATCH * (n + 1);
  float* Xo  = out;
  float* eP  = out + xe;
  float* Xc  = out + xe + 1;
  float* ecP = out + 2 * xe + 1;

  const int prepBlocks = (PREP_TOTAL + 255) / 256;
  prep_kernel<<<prepBlocks, 256, 0, stream>>>(w_in, b_in, w_hid, b_hid, w_out, b_out,
                                              variant, n, wsu, wsf);
  if (n == 16)
    layer0_kernel<16><<<NBLK, 256, 0, stream>>>(T, wsu, wsf, X1, scaleArr, n);
  else
    layer0_kernel<0><<<NBLK, 256, 0, stream>>>(T, wsu, wsf, X1, scaleArr, n);
  hidden_kernel<<<NBLK, 256, 0, stream>>>(X1, wsu + WH_OFF,          wsf + BH_F,       X2);
  hidden_kernel<<<NBLK, 256, 0, stream>>>(X2, wsu + WH_OFF + 262144, wsf + BH_F + 512, X3);
  if (n == 16)
    out_kernel<16><<<NBLK, 256, 0, stream>>>(T, X3, wsu, wsf, scaleArr, Xo, Xc, wsf + PART_F, n);
  else
    out_kernel<0><<<NBLK, 256, 0, stream>>>(T, X3, wsu, wsf, scaleArr, Xo, Xc, wsf + PART_F, n);
  finalize_kernel<<<1, 256, 0, stream>>>(wsf + PART_F, eP, ecP, 1.f / (float)((size_t)BATCH * n));
}

// Round 12
// 146.942 us; speedup vs baseline: 1.1348x; 1.1348x over previous
//
#include <hip/hip_runtime.h>

#define BATCH 65536
#define MT 64                 // rows per block
#define NBLK (BATCH / MT)     // 1024

typedef unsigned short u16;
typedef __bf16 bf16x8 __attribute__((ext_vector_type(8)));
typedef float f32x4 __attribute__((ext_vector_type(4)));

// d_ws layout (u16 element offsets)
// WI/WH tiles: [K32-tile][g(0..3)][col(0..511)][e(0..7)]  -> 16384 u16 = 32KB per K32 tile
// WO: fragment layout [K32][col(32)][g][e] (read direct from global)
#define WI_OFF 0              // 1 tile   (k>=16 zero)
#define WH_OFF 16384          // 32 tiles (2 layers x 16)
#define WO_OFF 540672
#define WS_USH 557056
// float region at (char*)ws + WS_USH*2
#define BI_F 0
#define BH_F 512
#define BO_F 1536
#define PART_F 1568           // [NBLK][2] per-block error partials
#define PREP_WH 65536
#define PREP_WI 2048
#define PREP_WO 2048
#define PREP_SC 1568
#define PREP_TOTAL (PREP_WH + PREP_WI + PREP_WO + PREP_SC)

__device__ inline u16 f2bf(float f) {
  union { float f; unsigned u; } v; v.f = f;
  unsigned u = v.u + 0x7fffu + ((v.u >> 16) & 1u);   // RNE
  return (u16)(u >> 16);
}

__global__ void prep_kernel(const float* __restrict__ w_in, const float* __restrict__ b_in,
                            const float* __restrict__ w_hid, const float* __restrict__ b_hid,
                            const float* __restrict__ w_out, const float* __restrict__ b_out,
                            const int* __restrict__ variant, int n,
                            u16* __restrict__ wsu, float* __restrict__ wsf)
{
  const int model = (n - 5) * 16 + variant[0];
  const int i = blockIdx.x * 256 + threadIdx.x;
  if (i < PREP_WH) {
    int col = i & 511, g = (i >> 9) & 3, K32 = (i >> 11) & 15, l = i >> 15;
    const float* src = w_hid + (size_t)model * 524288 + (size_t)l * 262144 + col * 512 + K32 * 32 + g * 8;
    u16* dst = wsu + WH_OFF + (size_t)i * 8;
    #pragma unroll
    for (int e = 0; e < 8; ++e) dst[e] = f2bf(src[e]);
  } else if (i < PREP_WH + PREP_WI) {
    int j = i - PREP_WH;
    int col = j & 511, g = (j >> 9) & 3;
    u16* dst = wsu + WI_OFF + (size_t)j * 8;
    #pragma unroll
    for (int e = 0; e < 8; ++e) {
      int k = g * 8 + e;
      dst[e] = (k < 16) ? f2bf(w_in[(size_t)model * 8192 + col * 16 + k]) : (u16)0;
    }
  } else if (i < PREP_WH + PREP_WI + PREP_WO) {
    int j = i - PREP_WH - PREP_WI;
    int g = j & 3, col = (j >> 2) & 31, K32 = j >> 7;
    u16* dst = wsu + WO_OFF + (size_t)j * 8;
    #pragma unroll
    for (int e = 0; e < 8; ++e) {
      int k = K32 * 32 + g * 8 + e;
      dst[e] = (col < 17) ? f2bf(w_out[(size_t)model * 8704 + col * 512 + k]) : (u16)0;
    }
  } else if (i < PREP_TOTAL) {
    int j = i - PREP_WH - PREP_WI - PREP_WO;
    if (j < 512)       wsf[BI_F + j] = b_in[(size_t)model * 512 + j];
    else if (j < 1536) wsf[BH_F + (j - 512)] = b_hid[(size_t)model * 1024 + (j - 512)];
    else               { int o = j - 1536; wsf[BO_F + o] = (o < 17) ? b_out[(size_t)model * 17 + o] : 0.f; }
  }
}

// xs layout: byte = row*1024 + ((col*2) ^ ((row&15)<<4))
__device__ __forceinline__ bf16x8 rdA(const char* xb, int row, int kbyte) {
  return *reinterpret_cast<const bf16x8*>(xb + row * 1024 + (kbyte ^ ((row & 15) << 4)));
}
__device__ __forceinline__ void st16(char* xb, int row, int col, u16 v) {
  *(u16*)(xb + row * 1024 + ((col * 2) ^ ((row & 15) << 4))) = v;
}

__device__ __forceinline__ void stage16(const u16* g, const u16* l) {
  __builtin_amdgcn_global_load_lds(
      (const __attribute__((address_space(1))) u16*)(uintptr_t)g,
      (__attribute__((address_space(3))) u16*)(unsigned)(uintptr_t)l,
      16, 0, 0);
}

template<int CN>
__global__ __launch_bounds__(512, 2) void fused_kernel(
    const float* __restrict__ T, const u16* __restrict__ wsu,
    const float* __restrict__ wsf, float* __restrict__ Xout, float* __restrict__ Xcout,
    float* __restrict__ errPart, int n_arg)
{
  const int n = CN ? CN : n_arg;
  __shared__ u16 xs[MT * 512];       // 64 KiB activations, XOR-swizzled
  __shared__ u16 bs[2 * 16384];      // 64 KiB: 2 x 32KB B-tiles (double buffer)
  __shared__ float xo[MT * 20];      // 5 KiB X_hat rows
  __shared__ float ts[MT * 16];      // 4 KiB T rows
  __shared__ float scaleS[MT];
  __shared__ float ered[8][2];

  const int tid = threadIdx.x;
  const int blk = blockIdx.x;
  const int lane = tid & 63;
  const int wid = tid >> 6;          // 0..7
  const int l15 = lane & 15;
  const int q = lane >> 4;           // 0..3
  const int c0 = wid * 64;           // wave's column base (hidden layers)
  char* xb = (char*)xs;
  char* bsB = (char*)bs;

  // W-frag byte offsets within a staged tile: [g=q][col][8e] -> stride-1, conflict-free
  int bofs[4];
  #pragma unroll
  for (int ct = 0; ct < 4; ++ct)
    bofs[ct] = q * 8192 + (c0 + ct * 16 + l15) * 16;

  auto stageTile = [&](int tau) {
    if (tau > 32) return;
    const u16* src = (tau == 0) ? (wsu + WI_OFF)
                   : (tau <= 16) ? (wsu + WH_OFF + (size_t)(tau - 1) * 16384)
                                 : (wsu + WH_OFF + 262144 + (size_t)(tau - 17) * 16384);
    char* dst = bsB + ((tau & 1) << 15);
    const char* s = (const char*)src;
    #pragma unroll
    for (int c = 0; c < 4; ++c) {
      int d = tid * 16 + c * 8192;
      stage16((const u16*)(s + d), (const u16*)(dst + d));
    }
  };

  f32x4 acc[4][4];
  #pragma unroll
  for (int a = 0; a < 4; ++a)
    #pragma unroll
    for (int b = 0; b < 4; ++b) { f32x4 z = {0.f, 0.f, 0.f, 0.f}; acc[a][b] = z; }

  // swapped operands: A = W-frag (lane -> outcol), B = X-frag (lane -> batch row)
  // => acc[mt][ct][j] = out[batch = mt*16 + l15][col = c0 + ct*16 + q*4 + j]
  auto computeTile = [&](int buf, int kbA) {
    const char* bb = bsB + (buf << 15);
    bf16x8 av[4], wv[4];
    #pragma unroll
    for (int mt = 0; mt < 4; ++mt) av[mt] = rdA(xb, mt * 16 + l15, kbA);
    #pragma unroll
    for (int ct = 0; ct < 4; ++ct) wv[ct] = *reinterpret_cast<const bf16x8*>(bb + bofs[ct]);
    __builtin_amdgcn_s_setprio(1);
    #pragma unroll
    for (int ct = 0; ct < 4; ++ct)
      #pragma unroll
      for (int mt = 0; mt < 4; ++mt)
        acc[mt][ct] = __builtin_amdgcn_mfma_f32_16x16x32_bf16(wv[ct], av[mt], acc[mt][ct], 0, 0, 0);
    __builtin_amdgcn_s_setprio(0);
  };

  // packed epilogue: lane holds 4 consecutive cols of one row -> ds_write_b64
  auto epilogue = [&](const float* bias, int act) {
    #pragma unroll
    for (int ct = 0; ct < 4; ++ct) {
      float4 bv = *reinterpret_cast<const float4*>(bias + c0 + ct * 16 + q * 4);
      const int colb = (c0 + ct * 16 + q * 4) * 2;
      #pragma unroll
      for (int mt = 0; mt < 4; ++mt) {
        int row = mt * 16 + l15;
        float z0 = acc[mt][ct][0] + bv.x;
        float z1 = acc[mt][ct][1] + bv.y;
        float z2 = acc[mt][ct][2] + bv.z;
        float z3 = acc[mt][ct][3] + bv.w;
        float h0, h1, h2, h3;
        if (act) {
          h0 = fmaxf(z0, 0.f); h1 = fmaxf(z1, 0.f); h2 = fmaxf(z2, 0.f); h3 = fmaxf(z3, 0.f);
        } else {
          h0 = z0 / (1.f + __expf(-z0)); h1 = z1 / (1.f + __expf(-z1));
          h2 = z2 / (1.f + __expf(-z2)); h3 = z3 / (1.f + __expf(-z3));
        }
        unsigned lo = (unsigned)f2bf(h0) | ((unsigned)f2bf(h1) << 16);
        unsigned hi = (unsigned)f2bf(h2) | ((unsigned)f2bf(h3) << 16);
        uint2 wv2; wv2.x = lo; wv2.y = hi;
        *reinterpret_cast<uint2*>(xb + row * 1024 + (colb ^ ((row & 15) << 4))) = wv2;
        f32x4 zz = {0.f, 0.f, 0.f, 0.f};
        acc[mt][ct] = zz;
      }
    }
  };

  // ---- issue first two B-tiles immediately ----
  stageTile(0);
  stageTile(1);

  // ---- prologue: T load + normalize; 8 threads/row ----
  {
    const int r = tid >> 3, j = tid & 7;
    const size_t gr = (size_t)blk * MT + r;
    const float* tp = T + gr * n;
    const int k0 = 2 * j, k1 = 2 * j + 1;
    float v0 = (k0 < n) ? tp[k0] : 0.f;
    float v1 = (k1 < n) ? tp[k1] : 0.f;
    float ss = v0 * v0 + v1 * v1;
    ss += __shfl_xor(ss, 1); ss += __shfl_xor(ss, 2); ss += __shfl_xor(ss, 4);
    float norm = sqrtf(ss < 1e-12f ? 1e-12f : ss);
    float rn = 1.f / norm;
    if (j == 0) scaleS[r] = sqrtf(norm);
    st16(xb, r, k0, f2bf(v0 * rn));
    st16(xb, r, k1, f2bf(v1 * rn));
    st16(xb, r, 16 + k0, 0);
    st16(xb, r, 16 + k1, 0);
    ts[r * 16 + k0] = v0;
    ts[r * 16 + k1] = v1;
  }

  // ---- L0 (WI, tile 0): one K=32 step ----
  asm volatile("s_waitcnt vmcnt(4) lgkmcnt(0)" ::: "memory");
  __builtin_amdgcn_s_barrier();
  computeTile(0, q * 16);
  __builtin_amdgcn_s_barrier();
  stageTile(2);
  epilogue(wsf + BI_F, 0);
  asm volatile("s_waitcnt lgkmcnt(0)" ::: "memory");
  __builtin_amdgcn_s_barrier();

  // ---- L1 (tiles 1..16) ----
  #pragma unroll 1
  for (int i = 0; i < 16; ++i) {
    asm volatile("s_waitcnt vmcnt(4)" ::: "memory");
    __builtin_amdgcn_s_barrier();
    computeTile((1 + i) & 1, i * 64 + q * 16);
    __builtin_amdgcn_s_barrier();
    stageTile(3 + i);
  }
  epilogue(wsf + BH_F, 1);
  asm volatile("s_waitcnt lgkmcnt(0)" ::: "memory");
  __builtin_amdgcn_s_barrier();

  // ---- L2 (tiles 17..32) ----
  #pragma unroll 1
  for (int i = 0; i < 15; ++i) {
    asm volatile("s_waitcnt vmcnt(4)" ::: "memory");
    __builtin_amdgcn_s_barrier();
    computeTile((17 + i) & 1, i * 64 + q * 16);
    __builtin_amdgcn_s_barrier();
    stageTile(19 + i);
  }
  asm volatile("s_waitcnt vmcnt(0)" ::: "memory");
  __builtin_amdgcn_s_barrier();
  computeTile(0, 15 * 64 + q * 16);
  __builtin_amdgcn_s_barrier();
  epilogue(wsf + BH_F + 512, 1);
  asm volatile("s_waitcnt lgkmcnt(0)" ::: "memory");
  __builtin_amdgcn_s_barrier();

  // ---- output layer (swapped): wave w -> rows (w>>1)*16..+16, col-half ch=w&1 ----
  {
    const int rg = wid >> 1;
    const int ch = wid & 1;
    f32x4 oacc = {0.f, 0.f, 0.f, 0.f};
    const u16* WoL = wsu + WO_OFF + (ch * 16 + l15) * 32 + q * 8;
    uint4 ob = *reinterpret_cast<const uint4*>(WoL);
    #pragma unroll 1
    for (int K = 0; K < 16; K += 2) {
      uint4 on = *reinterpret_cast<const uint4*>(WoL + (size_t)(K + 1) * 1024);
      {
        bf16x8 a0 = rdA(xb, rg * 16 + l15, K * 64 + q * 16);
        __builtin_amdgcn_s_setprio(1);
        oacc = __builtin_amdgcn_mfma_f32_16x16x32_bf16(__builtin_bit_cast(bf16x8, ob), a0, oacc, 0, 0, 0);
        __builtin_amdgcn_s_setprio(0);
      }
      ob = *reinterpret_cast<const uint4*>(WoL + (size_t)((K + 2) & 15) * 1024);
      {
        bf16x8 a1 = rdA(xb, rg * 16 + l15, (K + 1) * 64 + q * 16);
        __builtin_amdgcn_s_setprio(1);
        oacc = __builtin_amdgcn_mfma_f32_16x16x32_bf16(__builtin_bit_cast(bf16x8, on), a1, oacc, 0, 0, 0);
        __builtin_amdgcn_s_setprio(0);
      }
    }
    // lane: batch row = rg*16 + l15 (fixed), o = ch*16 + q*4 + j (consecutive)
    const int row = rg * 16 + l15;
    const size_t gr = (size_t)blk * MT + row;
    const float sc = scaleS[row];
    float4 bo = *reinterpret_cast<const float4*>(wsf + BO_F + ch * 16 + q * 4);
    float v0 = (oacc[0] + bo.x) * sc, v1 = (oacc[1] + bo.y) * sc;
    float v2 = (oacc[2] + bo.z) * sc, v3 = (oacc[3] + bo.w) * sc;
    float c0v = fminf(fmaxf(v0, -2.f), 2.f), c1v = fminf(fmaxf(v1, -2.f), 2.f);
    float c2v = fminf(fmaxf(v2, -2.f), 2.f), c3v = fminf(fmaxf(v3, -2.f), 2.f);
    const int ob0 = ch * 16 + q * 4;
    if (ch == 0) {
      float4 vv = {v0, v1, v2, v3};
      *reinterpret_cast<float4*>(&xo[row * 20 + ob0]) = vv;   // 16B-aligned
    }
    float vArr[4] = {v0, v1, v2, v3};
    float cArr[4] = {c0v, c1v, c2v, c3v};
    #pragma unroll
    for (int j = 0; j < 4; ++j) {
      int o = ob0 + j;
      if (o <= n) {
        Xout[gr * (n + 1) + o] = vArr[j];
        Xcout[gr * (n + 1) + o] = cArr[j];
        if (ch == 1) xo[row * 20 + o] = vArr[j];
      }
    }
  }
  __syncthreads();

  // ---- distortion + squared-error partials: 8 threads/row, T from LDS ----
  {
    const int r = tid >> 3, j = tid & 7;
    float x[17], cx[17];
    #pragma unroll
    for (int i = 0; i < 17; ++i) {
      float v = (i <= n) ? xo[r * 20 + i] : 0.f;
      x[i] = v; cx[i] = fminf(fmaxf(v, -2.f), 2.f);
    }
    float e = 0.f, ec = 0.f;
    #pragma unroll
    for (int kk = 0; kk < 2; ++kk) {
      int k = j + 1 + kk * 8;
      if (k <= n) {
        float d = 0.f, dc = 0.f;
        #pragma unroll
        for (int i = 0; i < 16; ++i) {
          if (i + k <= 16) {
            if (i + k <= n) { d += x[i] * x[i + k]; dc += cx[i] * cx[i + k]; }
          }
        }
        float tvv = ts[r * 16 + (n - k)];
        float r1 = d - tvv, r2 = dc - tvv;
        e += r1 * r1; ec += r2 * r2;
      }
    }
    e += __shfl_xor(e, 1);  ec += __shfl_xor(ec, 1);
    e += __shfl_xor(e, 2);  ec += __shfl_xor(ec, 2);
    e += __shfl_xor(e, 4);  ec += __shfl_xor(ec, 4);
    e += __shfl_xor(e, 8);  ec += __shfl_xor(ec, 8);
    e += __shfl_xor(e, 16); ec += __shfl_xor(ec, 16);
    e += __shfl_xor(e, 32); ec += __shfl_xor(ec, 32);
    if (lane == 0) { ered[wid][0] = e; ered[wid][1] = ec; }
  }
  __syncthreads();
  if (tid == 0) {
    float e = 0.f, ec = 0.f;
    #pragma unroll
    for (int w = 0; w < 8; ++w) { e += ered[w][0]; ec += ered[w][1]; }
    errPart[blk * 2]     = e;
    errPart[blk * 2 + 1] = ec;
  }
}

__global__ void finalize_kernel(const float* __restrict__ part, float* __restrict__ e0,
                                float* __restrict__ e1, float inv)
{
  __shared__ float se[4][2];
  const int t = threadIdx.x;           // 256 threads
  float e = 0.f, ec = 0.f;
  for (int b = t; b < NBLK; b += 256) { e += part[2 * b]; ec += part[2 * b + 1]; }
  e += __shfl_xor(e, 1);  ec += __shfl_xor(ec, 1);
  e += __shfl_xor(e, 2);  ec += __shfl_xor(ec, 2);
  e += __shfl_xor(e, 4);  ec += __shfl_xor(ec, 4);
  e += __shfl_xor(e, 8);  ec += __shfl_xor(ec, 8);
  e += __shfl_xor(e, 16); ec += __shfl_xor(ec, 16);
  e += __shfl_xor(e, 32); ec += __shfl_xor(ec, 32);
  if ((t & 63) == 0) { se[t >> 6][0] = e; se[t >> 6][1] = ec; }
  __syncthreads();
  if (t == 0) {
    float te = 0.f, tec = 0.f;
    #pragma unroll
    for (int w = 0; w < 4; ++w) { te += se[w][0]; tec += se[w][1]; }
    e0[0] = te * inv;
    e1[0] = tec * inv;
  }
}

extern "C" void kernel_launch(void* const* d_in, const int* in_sizes, int n_in,
                              void* d_out, int out_size, void* d_ws, size_t ws_size,
                              hipStream_t stream)
{
  const float* T       = (const float*)d_in[0];
  const int*   variant = (const int*)d_in[2];
  const float* w_in    = (const float*)d_in[3];
  const float* b_in    = (const float*)d_in[4];
  const float* w_hid   = (const float*)d_in[5];
  const float* b_hid   = (const float*)d_in[6];
  const float* w_out   = (const float*)d_in[7];
  const float* b_out   = (const float*)d_in[8];
  const int n = in_sizes[0] / BATCH;

  u16* wsu = (u16*)d_ws;
  float* wsf = (float*)((char*)d_ws + (size_t)WS_USH * 2);
  float* out = (float*)d_out;
  const size_t xe = (size_t)BATCH * (n + 1);
  float* Xo  = out;
  float* eP  = out + xe;
  float* Xc  = out + xe + 1;
  float* ecP = out + 2 * xe + 1;

  const int prepBlocks = (PREP_TOTAL + 255) / 256;
  prep_kernel<<<prepBlocks, 256, 0, stream>>>(w_in, b_in, w_hid, b_hid, w_out, b_out,
                                              variant, n, wsu, wsf);
  if (n == 16)
    fused_kernel<16><<<NBLK, 512, 0, stream>>>(T, wsu, wsf, Xo, Xc, wsf + PART_F, n);
  else
    fused_kernel<0><<<NBLK, 512, 0, stream>>>(T, wsu, wsf, Xo, Xc, wsf + PART_F, n);
  finalize_kernel<<<1, 256, 0, stream>>>(wsf + PART_F, eP, ecP, 1.f / (float)((size_t)BATCH * n));
}

// Round 13
// 132.196 us; speedup vs baseline: 1.2614x; 1.1116x over previous
//
#include <hip/hip_runtime.h>

#define BATCH 65536
#define MT 96                 // rows per block
#define NBLK 683              // ceil(65536/96); last block has 64 valid rows

typedef unsigned short u16;
typedef __bf16 bf16x8 __attribute__((ext_vector_type(8)));
typedef float f32x4 __attribute__((ext_vector_type(4)));

// d_ws layout (u16 element offsets)
// WI/WH tiles: [K32-tile][g(0..3)][col(0..511)][e(0..7)] -> 16384 u16 = 32KB per tile
// WO: fragment layout [K32][col(32)][g][e]
#define WI_OFF 0
#define WH_OFF 16384
#define WO_OFF 540672
#define WS_USH 557056
// float region at (char*)ws + WS_USH*2
#define BI_F 0
#define BH_F 512
#define BO_F 1536
#define PART_F 1600           // [NBLK][2]
#define SCALE_F 4096          // [65536+32]
#define PREP_WH 65536
#define PREP_WI 2048
#define PREP_WO 2048
#define PREP_SC 1568
#define PREP_TOTAL (PREP_WH + PREP_WI + PREP_WO + PREP_SC)

__device__ inline u16 f2bf(float f) {
  union { float f; unsigned u; } v; v.f = f;
  unsigned u = v.u + 0x7fffu + ((v.u >> 16) & 1u);   // RNE
  return (u16)(u >> 16);
}

__global__ void prep_kernel(const float* __restrict__ w_in, const float* __restrict__ b_in,
                            const float* __restrict__ w_hid, const float* __restrict__ b_hid,
                            const float* __restrict__ w_out, const float* __restrict__ b_out,
                            const int* __restrict__ variant, int n,
                            u16* __restrict__ wsu, float* __restrict__ wsf)
{
  const int model = (n - 5) * 16 + variant[0];
  const int i = blockIdx.x * 256 + threadIdx.x;
  if (i < PREP_WH) {
    int col = i & 511, g = (i >> 9) & 3, K32 = (i >> 11) & 15, l = i >> 15;
    const float* src = w_hid + (size_t)model * 524288 + (size_t)l * 262144 + col * 512 + K32 * 32 + g * 8;
    u16* dst = wsu + WH_OFF + (size_t)i * 8;
    #pragma unroll
    for (int e = 0; e < 8; ++e) dst[e] = f2bf(src[e]);
  } else if (i < PREP_WH + PREP_WI) {
    int j = i - PREP_WH;
    int col = j & 511, g = (j >> 9) & 3;
    u16* dst = wsu + WI_OFF + (size_t)j * 8;
    #pragma unroll
    for (int e = 0; e < 8; ++e) {
      int k = g * 8 + e;
      dst[e] = (k < 16) ? f2bf(w_in[(size_t)model * 8192 + col * 16 + k]) : (u16)0;
    }
  } else if (i < PREP_WH + PREP_WI + PREP_WO) {
    int j = i - PREP_WH - PREP_WI;
    int g = j & 3, col = (j >> 2) & 31, K32 = j >> 7;
    u16* dst = wsu + WO_OFF + (size_t)j * 8;
    #pragma unroll
    for (int e = 0; e < 8; ++e) {
      int k = K32 * 32 + g * 8 + e;
      dst[e] = (col < 17) ? f2bf(w_out[(size_t)model * 8704 + col * 512 + k]) : (u16)0;
    }
  } else if (i < PREP_TOTAL) {
    int j = i - PREP_WH - PREP_WI - PREP_WO;
    if (j < 512)       wsf[BI_F + j] = b_in[(size_t)model * 512 + j];
    else if (j < 1536) wsf[BH_F + (j - 512)] = b_hid[(size_t)model * 1024 + (j - 512)];
    else               { int o = j - 1536; wsf[BO_F + o] = (o < 17) ? b_out[(size_t)model * 17 + o] : 0.f; }
  }
}

// xs layout: byte = row*1024 + ((col*2) ^ ((row&15)<<4))
__device__ __forceinline__ bf16x8 rdA(const char* xb, int row, int kbyte) {
  return *reinterpret_cast<const bf16x8*>(xb + row * 1024 + (kbyte ^ ((row & 15) << 4)));
}
__device__ __forceinline__ void st16(char* xb, int row, int col, u16 v) {
  *(u16*)(xb + row * 1024 + ((col * 2) ^ ((row & 15) << 4))) = v;
}

__device__ __forceinline__ void stage16(const u16* g, const u16* l) {
  __builtin_amdgcn_global_load_lds(
      (const __attribute__((address_space(1))) u16*)(uintptr_t)g,
      (__attribute__((address_space(3))) u16*)(unsigned)(uintptr_t)l,
      16, 0, 0);
}

template<int CN>
__global__ __launch_bounds__(512, 2) void fused_kernel(
    const float* __restrict__ T, const u16* __restrict__ wsu,
    const float* __restrict__ wsf, float* __restrict__ Xout, float* __restrict__ Xcout,
    float* __restrict__ errPart, float* __restrict__ scaleArr, int n_arg)
{
  const int n = CN ? CN : n_arg;
  __shared__ u16 xs[MT * 512];       // 96 KiB activations, XOR-swizzled
  __shared__ u16 bs[2 * 16384];      // 64 KiB: 2 x 32KB B-tiles (double buffer)
  // total LDS = 163840 B = full 160 KiB pool; xo/ered overlay bs after K-loops

  const int tid = threadIdx.x;
  const int blk = blockIdx.x;
  const int lane = tid & 63;
  const int wid = tid >> 6;          // 0..7
  const int l15 = lane & 15;
  const int q = lane >> 4;           // 0..3
  const int c0 = wid * 64;           // wave's column base (hidden layers)
  char* xb = (char*)xs;
  char* bsB = (char*)bs;

  // W-frag byte offsets within a staged tile: [g=q][col][8e] -> stride-1, conflict-free
  int bofs[4];
  #pragma unroll
  for (int ct = 0; ct < 4; ++ct)
    bofs[ct] = q * 8192 + (c0 + ct * 16 + l15) * 16;

  auto stageTile = [&](int tau) {
    if (tau > 32) return;
    const u16* src = (tau == 0) ? (wsu + WI_OFF)
                   : (tau <= 16) ? (wsu + WH_OFF + (size_t)(tau - 1) * 16384)
                                 : (wsu + WH_OFF + 262144 + (size_t)(tau - 17) * 16384);
    char* dst = bsB + ((tau & 1) << 15);
    const char* s = (const char*)src;
    #pragma unroll
    for (int c = 0; c < 4; ++c) {
      int d = tid * 16 + c * 8192;
      stage16((const u16*)(s + d), (const u16*)(dst + d));
    }
  };

  f32x4 acc[6][4];
  #pragma unroll
  for (int a = 0; a < 6; ++a)
    #pragma unroll
    for (int b = 0; b < 4; ++b) { f32x4 z = {0.f, 0.f, 0.f, 0.f}; acc[a][b] = z; }

  auto computeTile = [&](int buf, int kbA) {
    const char* bb = bsB + (buf << 15);
    bf16x8 av[6];
    #pragma unroll
    for (int mt = 0; mt < 6; ++mt) av[mt] = rdA(xb, mt * 16 + l15, kbA);
    #pragma unroll
    for (int ct = 0; ct < 4; ++ct) {
      bf16x8 b = *reinterpret_cast<const bf16x8*>(bb + bofs[ct]);
      #pragma unroll
      for (int mt = 0; mt < 6; ++mt)
        acc[mt][ct] = __builtin_amdgcn_mfma_f32_16x16x32_bf16(av[mt], b, acc[mt][ct], 0, 0, 0);
    }
  };

  auto epilogue = [&](const float* bias, int act) {
    float bv[4];
    #pragma unroll
    for (int ct = 0; ct < 4; ++ct) bv[ct] = bias[c0 + ct * 16 + l15];
    #pragma unroll
    for (int mt = 0; mt < 6; ++mt)
      #pragma unroll
      for (int ct = 0; ct < 4; ++ct) {
        #pragma unroll
        for (int j = 0; j < 4; ++j) {
          int row = mt * 16 + q * 4 + j;
          float z = acc[mt][ct][j] + bv[ct];
          float h = act ? fmaxf(z, 0.f) : z / (1.f + __expf(-z));
          st16(xb, row, c0 + ct * 16 + l15, f2bf(h));
        }
        f32x4 zz = {0.f, 0.f, 0.f, 0.f};
        acc[mt][ct] = zz;
      }
  };

  // ---- issue first two B-tiles immediately ----
  stageTile(0);
  stageTile(1);

  // ---- prologue: T load + normalize; 4 threads/row (384 active) ----
  {
    const int r = tid >> 2, j = tid & 3;
    if (r < MT) {
      const size_t gr = (size_t)blk * MT + r;
      const bool valid = gr < (size_t)BATCH;
      const float* tp = T + gr * n;
      float v[4]; float ss = 0.f;
      #pragma unroll
      for (int c = 0; c < 4; ++c) {
        int k = j * 4 + c;
        v[c] = (valid && k < n) ? tp[k] : 0.f;
        ss += v[c] * v[c];
      }
      ss += __shfl_xor(ss, 1); ss += __shfl_xor(ss, 2);
      float norm = sqrtf(ss < 1e-12f ? 1e-12f : ss);
      float rn = 1.f / norm;
      if (j == 0 && valid) scaleArr[gr] = sqrtf(norm);
      #pragma unroll
      for (int c = 0; c < 4; ++c) {
        st16(xb, r, j * 4 + c, f2bf(v[c] * rn));
        st16(xb, r, 16 + j * 4 + c, 0);
      }
    }
  }

  // ---- L0 (WI, tile 0): one K=32 step ----
  asm volatile("s_waitcnt vmcnt(4) lgkmcnt(0)" ::: "memory");
  __builtin_amdgcn_s_barrier();
  computeTile(0, q * 16);
  __builtin_amdgcn_s_barrier();
  stageTile(2);
  epilogue(wsf + BI_F, 0);
  asm volatile("s_waitcnt lgkmcnt(0)" ::: "memory");
  __builtin_amdgcn_s_barrier();

  // ---- L1 (tiles 1..16) ----
  #pragma unroll 1
  for (int i = 0; i < 16; ++i) {
    asm volatile("s_waitcnt vmcnt(4)" ::: "memory");
    __builtin_amdgcn_s_barrier();
    computeTile((1 + i) & 1, i * 64 + q * 16);
    __builtin_amdgcn_s_barrier();
    stageTile(3 + i);
  }
  epilogue(wsf + BH_F, 1);
  asm volatile("s_waitcnt lgkmcnt(0)" ::: "memory");
  __builtin_amdgcn_s_barrier();

  // ---- L2 (tiles 17..32) ----
  #pragma unroll 1
  for (int i = 0; i < 15; ++i) {
    asm volatile("s_waitcnt vmcnt(4)" ::: "memory");
    __builtin_amdgcn_s_barrier();
    computeTile((17 + i) & 1, i * 64 + q * 16);
    __builtin_amdgcn_s_barrier();
    stageTile(19 + i);
  }
  asm volatile("s_waitcnt vmcnt(0)" ::: "memory");
  __builtin_amdgcn_s_barrier();
  computeTile(0, 15 * 64 + q * 16);
  __builtin_amdgcn_s_barrier();
  epilogue(wsf + BH_F + 512, 1);
  asm volatile("s_waitcnt lgkmcnt(0)" ::: "memory");
  __builtin_amdgcn_s_barrier();
  // bs is now dead: overlay xo (96*20 floats) + ered (16 floats)
  float* xoB  = reinterpret_cast<float*>(bs);
  float* ered = xoB + MT * 20;

  // ---- output layer: waves 0..5, wave w -> rows w*16..+16, 32 padded cols ----
  if (wid < 6) {
    f32x4 oacc[2];
    { f32x4 z = {0.f, 0.f, 0.f, 0.f}; oacc[0] = z; oacc[1] = z; }
    const int bofs2 = l15 * 32 + q * 8;
    uint4 ob[2], on[2];
    #pragma unroll
    for (int ct = 0; ct < 2; ++ct)
      ob[ct] = *reinterpret_cast<const uint4*>(wsu + WO_OFF + (size_t)(ct * 16) * 32 + bofs2);
    #pragma unroll 1
    for (int K2 = 0; K2 < 16; K2 += 2) {
      #pragma unroll
      for (int ct = 0; ct < 2; ++ct)
        on[ct] = *reinterpret_cast<const uint4*>(wsu + WO_OFF + (size_t)(K2 + 1) * 1024 + (size_t)(ct * 16) * 32 + bofs2);
      {
        bf16x8 a = rdA(xb, wid * 16 + l15, K2 * 64 + q * 16);
        #pragma unroll
        for (int ct = 0; ct < 2; ++ct)
          oacc[ct] = __builtin_amdgcn_mfma_f32_16x16x32_bf16(
              a, __builtin_bit_cast(bf16x8, ob[ct]), oacc[ct], 0, 0, 0);
      }
      #pragma unroll
      for (int ct = 0; ct < 2; ++ct)
        ob[ct] = *reinterpret_cast<const uint4*>(wsu + WO_OFF + (size_t)((K2 + 2) & 15) * 1024 + (size_t)(ct * 16) * 32 + bofs2);
      {
        bf16x8 a = rdA(xb, wid * 16 + l15, (K2 + 1) * 64 + q * 16);
        #pragma unroll
        for (int ct = 0; ct < 2; ++ct)
          oacc[ct] = __builtin_amdgcn_mfma_f32_16x16x32_bf16(
              a, __builtin_bit_cast(bf16x8, on[ct]), oacc[ct], 0, 0, 0);
      }
    }
    #pragma unroll
    for (int ct = 0; ct < 2; ++ct)
      #pragma unroll
      for (int j = 0; j < 4; ++j) {
        int o = ct * 16 + l15;
        int row = wid * 16 + q * 4 + j;
        size_t gr = (size_t)blk * MT + row;
        if (o <= n && gr < (size_t)BATCH) {
          float val = (oacc[ct][j] + wsf[BO_F + o]) * scaleArr[gr];
          float cv = fminf(fmaxf(val, -2.f), 2.f);
          Xout[gr * (n + 1) + o] = val;
          Xcout[gr * (n + 1) + o] = cv;
          xoB[row * 20 + o] = val;
        }
      }
  }
  __syncthreads();

  // ---- distortion + squared-error partials: 4 threads/row (384 active) ----
  {
    const int r = tid >> 2, j = tid & 3;
    float e = 0.f, ec = 0.f;
    if (r < MT) {
      const size_t gr = (size_t)blk * MT + r;
      if (gr < (size_t)BATCH) {
        float x[17], cx[17];
        #pragma unroll
        for (int i = 0; i < 17; ++i) {
          float v = (i <= n) ? xoB[r * 20 + i] : 0.f;
          x[i] = v; cx[i] = fminf(fmaxf(v, -2.f), 2.f);
        }
        #pragma unroll
        for (int kk = 0; kk < 4; ++kk) {
          int k = j + 1 + kk * 4;
          if (k <= n) {
            float d = 0.f, dc = 0.f;
            #pragma unroll
            for (int i = 0; i < 16; ++i) {
              if (i + k <= 16) {
                if (i + k <= n) { d += x[i] * x[i + k]; dc += cx[i] * cx[i + k]; }
              }
            }
            float tvv = T[gr * n + (n - k)];
            float r1 = d - tvv, r2 = dc - tvv;
            e += r1 * r1; ec += r2 * r2;
          }
        }
      }
    }
    e += __shfl_xor(e, 1);  ec += __shfl_xor(ec, 1);
    e += __shfl_xor(e, 2);  ec += __shfl_xor(ec, 2);
    e += __shfl_xor(e, 4);  ec += __shfl_xor(ec, 4);
    e += __shfl_xor(e, 8);  ec += __shfl_xor(ec, 8);
    e += __shfl_xor(e, 16); ec += __shfl_xor(ec, 16);
    e += __shfl_xor(e, 32); ec += __shfl_xor(ec, 32);
    if (lane == 0) { ered[wid * 2] = e; ered[wid * 2 + 1] = ec; }
  }
  __syncthreads();
  if (tid == 0) {
    float e = 0.f, ec = 0.f;
    #pragma unroll
    for (int w = 0; w < 8; ++w) { e += ered[w * 2]; ec += ered[w * 2 + 1]; }
    errPart[blk * 2]     = e;
    errPart[blk * 2 + 1] = ec;
  }
}

__global__ void finalize_kernel(const float* __restrict__ part, float* __restrict__ e0,
                                float* __restrict__ e1, float inv)
{
  __shared__ float se[4][2];
  const int t = threadIdx.x;           // 256 threads
  float e = 0.f, ec = 0.f;
  for (int b = t; b < NBLK; b += 256) { e += part[2 * b]; ec += part[2 * b + 1]; }
  e += __shfl_xor(e, 1);  ec += __shfl_xor(ec, 1);
  e += __shfl_xor(e, 2);  ec += __shfl_xor(ec, 2);
  e += __shfl_xor(e, 4);  ec += __shfl_xor(ec, 4);
  e += __shfl_xor(e, 8);  ec += __shfl_xor(ec, 8);
  e += __shfl_xor(e, 16); ec += __shfl_xor(ec, 16);
  e += __shfl_xor(e, 32); ec += __shfl_xor(ec, 32);
  if ((t & 63) == 0) { se[t >> 6][0] = e; se[t >> 6][1] = ec; }
  __syncthreads();
  if (t == 0) {
    float te = 0.f, tec = 0.f;
    #pragma unroll
    for (int w = 0; w < 4; ++w) { te += se[w][0]; tec += se[w][1]; }
    e0[0] = te * inv;
    e1[0] = tec * inv;
  }
}

extern "C" void kernel_launch(void* const* d_in, const int* in_sizes, int n_in,
                              void* d_out, int out_size, void* d_ws, size_t ws_size,
                              hipStream_t stream)
{
  const float* T       = (const float*)d_in[0];
  const int*   variant = (const int*)d_in[2];
  const float* w_in    = (const float*)d_in[3];
  const float* b_in    = (const float*)d_in[4];
  const float* w_hid   = (const float*)d_in[5];
  const float* b_hid   = (const float*)d_in[6];
  const float* w_out   = (const float*)d_in[7];
  const float* b_out   = (const float*)d_in[8];
  const int n = in_sizes[0] / BATCH;

  u16* wsu = (u16*)d_ws;
  float* wsf = (float*)((char*)d_ws + (size_t)WS_USH * 2);
  float* out = (float*)d_out;
  const size_t xe = (size_t)BATCH * (n + 1);
  float* Xo  = out;
  float* eP  = out + xe;
  float* Xc  = out + xe + 1;
  float* ecP = out + 2 * xe + 1;

  const int prepBlocks = (PREP_TOTAL + 255) / 256;
  prep_kernel<<<prepBlocks, 256, 0, stream>>>(w_in, b_in, w_hid, b_hid, w_out, b_out,
                                              variant, n, wsu, wsf);
  if (n == 16)
    fused_kernel<16><<<NBLK, 512, 0, stream>>>(T, wsu, wsf, Xo, Xc, wsf + PART_F,
                                               wsf + SCALE_F, n);
  else
    fused_kernel<0><<<NBLK, 512, 0, stream>>>(T, wsu, wsf, Xo, Xc, wsf + PART_F,
                                              wsf + SCALE_F, n);
  finalize_kernel<<<1, 256, 0, stream>>>(wsf + PART_F, eP, ecP, 1.f / (float)((size_t)BATCH * n));
}